// Round 2
// baseline (732.034 us; speedup 1.0000x reference)
//
#include <hip/hip_runtime.h>
#include <hip/hip_bf16.h>

#define B_ 4
#define N_ 2048
#define C_ 256
#define H_ 8
#define DH_ 32
#define SCALE_ 0.17677669529663687f

typedef __attribute__((ext_vector_type(8))) short bf16x8;
typedef __attribute__((ext_vector_type(4))) float f32x4;

__device__ __forceinline__ short f2bf(float f) {
    union { float f; unsigned u; } v; v.f = f;
    unsigned r = v.u + 0x7fffu + ((v.u >> 16) & 1u);
    return (short)(r >> 16);
}
__device__ __forceinline__ float bf2f(short s) {
    union { unsigned u; float f; } v; v.u = ((unsigned)(unsigned short)s) << 16;
    return v.f;
}
// pack 8 fp32 -> bf16x8 via v_cvt_pk_bf16_f32 (RNE, matches f2bf)
__device__ __forceinline__ bf16x8 cvt_pk8(f32x4 a, f32x4 b) {
    union { unsigned u[4]; bf16x8 v; } r;
    asm("v_cvt_pk_bf16_f32 %0, %1, %2" : "=v"(r.u[0]) : "v"(a[0]), "v"(a[1]));
    asm("v_cvt_pk_bf16_f32 %0, %1, %2" : "=v"(r.u[1]) : "v"(a[2]), "v"(a[3]));
    asm("v_cvt_pk_bf16_f32 %0, %1, %2" : "=v"(r.u[2]) : "v"(b[0]), "v"(b[1]));
    asm("v_cvt_pk_bf16_f32 %0, %1, %2" : "=v"(r.u[3]) : "v"(b[2]), "v"(b[3]));
    return r.v;
}

// ---------------- K1: QKV projection (hi/lo split bf16 MFMA) ----------------
// x[8192,256] @ W_qkv[256,768] -> q(scaled),k bf16 [bh][n][32], v transposed [bh][32][n]
__global__ __launch_bounds__(256) void k_qkv(
    const float* __restrict__ x, const float* __restrict__ Wq,
    short* __restrict__ qbf, short* __restrict__ kbf, short* __restrict__ vtbf)
{
    __shared__ __align__(16) short XSh[64*40], XSl[64*40];   // 64 rows x 32, stride 40 (80B)
    __shared__ __align__(16) short WTh[128*40], WTl[128*40]; // 128 cols x 32k, transposed
    const int tid = threadIdx.x;
    const int wid = tid >> 6, lane = tid & 63;
    const int l15 = lane & 15, quad = lane >> 4;
    const int r0 = blockIdx.y * 64;
    const int c0 = blockIdx.x * 128;

    f32x4 acc[8];
    #pragma unroll
    for (int t = 0; t < 8; ++t) acc[t] = (f32x4){0.f,0.f,0.f,0.f};

    for (int kk = 0; kk < 8; ++kk) {
        const int k0 = kk * 32;
        { // stage X tile 64x32 fp32 -> hi/lo bf16
            int row = tid >> 2, cg = tid & 3;
            const float* xp = &x[(size_t)(r0 + row) * C_ + k0 + cg * 8];
            float4 a = *(const float4*)xp;
            float4 b = *(const float4*)(xp + 4);
            float vals[8] = {a.x,a.y,a.z,a.w,b.x,b.y,b.z,b.w};
            short hi[8], lo[8];
            #pragma unroll
            for (int i = 0; i < 8; ++i) {
                hi[i] = f2bf(vals[i]);
                lo[i] = f2bf(vals[i] - bf2f(hi[i]));
            }
            *(bf16x8*)&XSh[row*40 + cg*8] = *(bf16x8*)hi;
            *(bf16x8*)&XSl[row*40 + cg*8] = *(bf16x8*)lo;
        }
        { // stage W tile 32x128 transposed
            int wrow = tid >> 3, seg = tid & 7;
            const float* wp = &Wq[(size_t)(k0 + wrow) * (3*C_) + c0 + seg*16];
            #pragma unroll
            for (int q4 = 0; q4 < 4; ++q4) {
                float4 wv = *(const float4*)(wp + q4*4);
                float wa[4] = {wv.x, wv.y, wv.z, wv.w};
                #pragma unroll
                for (int i = 0; i < 4; ++i) {
                    int col = seg*16 + q4*4 + i;
                    short hb = f2bf(wa[i]);
                    WTh[col*40 + wrow] = hb;
                    WTl[col*40 + wrow] = f2bf(wa[i] - bf2f(hb));
                }
            }
        }
        __syncthreads();
        bf16x8 ah = *(bf16x8*)&XSh[(wid*16 + l15)*40 + quad*8];
        bf16x8 al = *(bf16x8*)&XSl[(wid*16 + l15)*40 + quad*8];
        #pragma unroll
        for (int t = 0; t < 8; ++t) {
            bf16x8 bh = *(bf16x8*)&WTh[(t*16 + l15)*40 + quad*8];
            bf16x8 bl = *(bf16x8*)&WTl[(t*16 + l15)*40 + quad*8];
            acc[t] = __builtin_amdgcn_mfma_f32_16x16x32_bf16(ah, bh, acc[t], 0,0,0);
            acc[t] = __builtin_amdgcn_mfma_f32_16x16x32_bf16(ah, bl, acc[t], 0,0,0);
            acc[t] = __builtin_amdgcn_mfma_f32_16x16x32_bf16(al, bh, acc[t], 0,0,0);
        }
        __syncthreads();
    }
    // scatter store: col j -> (which, h, d)
    #pragma unroll
    for (int t = 0; t < 8; ++t) {
        int j = c0 + t*16 + l15;
        int which = j >> 8, h = (j >> 5) & 7, d = j & 31;
        #pragma unroll
        for (int r = 0; r < 4; ++r) {
            int tok = r0 + wid*16 + quad*4 + r;
            int b = tok >> 11, n = tok & (N_-1);
            float val = acc[t][r];
            int bh = b * H_ + h;
            if (which == 0)      qbf[((size_t)bh * N_ + n) * DH_ + d] = f2bf(val * SCALE_);
            else if (which == 1) kbf[((size_t)bh * N_ + n) * DH_ + d] = f2bf(val);
            else                 vtbf[((size_t)bh * DH_ + d) * N_ + n] = f2bf(val);
        }
    }
}

// ---------------- K2: softmax denominators (1/Z per global row) ----------------
__global__ __launch_bounds__(256) void k_zsum(
    const short* __restrict__ qbf, const short* __restrict__ kbf,
    float* __restrict__ zrecip)
{
    const int tid = threadIdx.x;
    const int wid = tid >> 6, lane = tid & 63;
    const int l15 = lane & 15, quad = lane >> 4;
    const int bh = blockIdx.y;
    const int q0 = blockIdx.x * 64 + wid * 16;

    bf16x8 aq = *(const bf16x8*)&qbf[((size_t)bh * N_ + q0 + l15) * DH_ + quad * 8];
    float zs[4] = {0.f, 0.f, 0.f, 0.f};
    const short* kbase = &kbf[(size_t)bh * N_ * DH_];
    #pragma unroll 4
    for (int mt = 0; mt < N_/16; ++mt) {
        bf16x8 bk = *(const bf16x8*)&kbase[(mt*16 + l15) * DH_ + quad * 8];
        f32x4 S = __builtin_amdgcn_mfma_f32_16x16x32_bf16(aq, bk, (f32x4){0,0,0,0}, 0,0,0);
        zs[0] += __expf(S[0]); zs[1] += __expf(S[1]);
        zs[2] += __expf(S[2]); zs[3] += __expf(S[3]);
    }
    #pragma unroll
    for (int r = 0; r < 4; ++r)
        for (int off = 1; off < 16; off <<= 1)
            zs[r] += __shfl_xor(zs[r], off, 64);
    if (l15 == 0) {
        #pragma unroll
        for (int r = 0; r < 4; ++r)
            zrecip[(size_t)bh * N_ + q0 + quad*4 + r] = 1.0f / zs[r];
    }
}

// ---------------- K3: main attention: fp32 P tile in LDS, wide wout stores, cvt_pk PV frag ----------------
__global__ __launch_bounds__(256) void k_attn(
    const short* __restrict__ qbf, const short* __restrict__ kbf,
    const short* __restrict__ vtbf, const float* __restrict__ zrecip,
    float* __restrict__ wout, short* __restrict__ xc)
{
    // per-wave fp32 normalized P tile [16 rows][32 cols], row stride 36 floats (144B):
    //  - writes (row=quad*4+r, col=l15 / 16+l15): banks (4q+4r... ) -> max 2-way = free
    //  - reads  (row=l15, cols=quad*8..+7) as 2x ds_read_b128, 16B-aligned
    __shared__ __align__(16) float pt[4][16*36];
    const int tid = threadIdx.x;
    const int wid = tid >> 6, lane = tid & 63;
    const int l15 = lane & 15, quad = lane >> 4;
    const int bh = blockIdx.y;
    const int b = bh >> 3, h = bh & 7;
    const int q0 = blockIdx.x * 64 + wid * 16;
    const int w = q0 >> 4;            // local window index (16 rows == 1 window)
    const int mtd = w >> 1, hl = w & 1;

    bf16x8 aq = *(const bf16x8*)&qbf[((size_t)bh * N_ + q0 + l15) * DH_ + quad * 8];
    float zr[4];
    #pragma unroll
    for (int r = 0; r < 4; ++r) zr[r] = zrecip[(size_t)bh * N_ + q0 + quad*4 + r];

    const short* kbase = &kbf[(size_t)bh * N_ * DH_];
    const short* vbase = &vtbf[(size_t)bh * DH_ * N_];
    float* wbase = &wout[((size_t)bh * N_ + q0) * N_];

    f32x4 O0 = {0,0,0,0}, O1 = {0,0,0,0};
    float pl[4] = {0.f,0.f,0.f,0.f};
    float* myp = pt[wid];
    // loop-invariant addresses
    float*       wr0  = &myp[(quad*4)*36 + l15];     // + r*36 (+16 for upper 16 cols)
    const float* rd   = &myp[l15*36 + quad*8];       // row l15, 8 floats at col quad*8
    float*       wrow = wbase + (size_t)l15 * N_ + quad*8;  // wout row l15, col quad*8

    for (int mt = 0; mt < N_/32; ++mt) {
        const int m0 = mt * 32;
        bf16x8 bk0 = *(const bf16x8*)&kbase[(size_t)(m0 + l15) * DH_ + quad * 8];
        bf16x8 bk1 = *(const bf16x8*)&kbase[(size_t)(m0 + 16 + l15) * DH_ + quad * 8];
        f32x4 S0 = __builtin_amdgcn_mfma_f32_16x16x32_bf16(aq, bk0, (f32x4){0,0,0,0}, 0,0,0);
        f32x4 S1 = __builtin_amdgcn_mfma_f32_16x16x32_bf16(aq, bk1, (f32x4){0,0,0,0}, 0,0,0);
        float p0[4], p1[4];
        #pragma unroll
        for (int r = 0; r < 4; ++r) { p0[r] = __expf(S0[r]); p1[r] = __expf(S1[r]); }
        if (mt == mtd) {
            #pragma unroll
            for (int r = 0; r < 4; ++r) pl[r] = hl ? p1[r] : p0[r];
        }
        #pragma unroll
        for (int r = 0; r < 4; ++r) {
            wr0[r*36]      = p0[r] * zr[r];
            wr0[r*36 + 16] = p1[r] * zr[r];
        }
        // one LDS readback feeds BOTH the wide wout store and the PV A-fragment
        f32x4 pa0 = *(const f32x4*)rd;
        f32x4 pa1 = *(const f32x4*)(rd + 4);
        __builtin_nontemporal_store(pa0, (f32x4*)(wrow + m0));
        __builtin_nontemporal_store(pa1, (f32x4*)(wrow + m0 + 4));
        bf16x8 ap = cvt_pk8(pa0, pa1);
        bf16x8 bv0 = *(const bf16x8*)&vbase[(size_t)l15 * N_ + m0 + quad*8];
        bf16x8 bv1 = *(const bf16x8*)&vbase[(size_t)(16 + l15) * N_ + m0 + quad*8];
        O0 = __builtin_amdgcn_mfma_f32_16x16x32_bf16(ap, bv0, O0, 0,0,0);
        O1 = __builtin_amdgcn_mfma_f32_16x16x32_bf16(ap, bv1, O1, 0,0,0);
    }

    // local window attention (reuses stashed diagonal exp tile, unnormalized)
    float zl[4];
    #pragma unroll
    for (int r = 0; r < 4; ++r) {
        zl[r] = pl[r];
        for (int off = 1; off < 16; off <<= 1)
            zl[r] += __shfl_xor(zl[r], off, 64);
    }
    #pragma unroll
    for (int r = 0; r < 4; ++r) {
        float pn = pl[r] / zl[r];
        wr0[r*36]      = hl ? 0.f : pn;
        wr0[r*36 + 16] = hl ? pn : 0.f;
    }
    {
        const int m0 = mtd * 32;
        f32x4 pa0 = *(const f32x4*)rd;
        f32x4 pa1 = *(const f32x4*)(rd + 4);
        bf16x8 ap = cvt_pk8(pa0, pa1);
        bf16x8 bv0 = *(const bf16x8*)&vbase[(size_t)l15 * N_ + m0 + quad*8];
        bf16x8 bv1 = *(const bf16x8*)&vbase[(size_t)(16 + l15) * N_ + m0 + quad*8];
        O0 = __builtin_amdgcn_mfma_f32_16x16x32_bf16(ap, bv0, O0, 0,0,0);
        O1 = __builtin_amdgcn_mfma_f32_16x16x32_bf16(ap, bv1, O1, 0,0,0);
    }
    // store x_comb (bf16) in [B,N,C] head-merged layout
    #pragma unroll
    for (int r = 0; r < 4; ++r) {
        int n = q0 + quad*4 + r;
        short* xrow = &xc[((size_t)(b * N_ + n)) * C_ + h * DH_];
        xrow[l15]      = f2bf(O0[r]);
        xrow[16 + l15] = f2bf(O1[r]);
    }
}

// ---------------- K4: output projection + bias ----------------
__global__ __launch_bounds__(256) void k_proj(
    const short* __restrict__ xc, const float* __restrict__ Wp,
    const float* __restrict__ bp, float* __restrict__ out)
{
    __shared__ __align__(16) short WT[64 * 264];  // 64 cols x 256 k, stride 528B
    const int tid = threadIdx.x;
    const int wid = tid >> 6, lane = tid & 63;
    const int l15 = lane & 15, quad = lane >> 4;
    const int c0 = blockIdx.x * 64;
    const int r0 = blockIdx.y * 64;

    { // stage W_proj[:, c0:c0+64] transposed
        int k = tid;
        const float* wp = &Wp[(size_t)k * C_ + c0];
        #pragma unroll
        for (int s = 0; s < 16; ++s) {
            float4 wv = *(const float4*)(wp + s*4);
            float wa[4] = {wv.x, wv.y, wv.z, wv.w};
            #pragma unroll
            for (int i = 0; i < 4; ++i)
                WT[(s*4 + i) * 264 + k] = f2bf(wa[i]);
        }
    }
    __syncthreads();

    f32x4 acc[4];
    #pragma unroll
    for (int t = 0; t < 4; ++t) acc[t] = (f32x4){0,0,0,0};
    const short* xrow = &xc[(size_t)(r0 + wid*16 + l15) * C_];
    #pragma unroll
    for (int kk = 0; kk < 8; ++kk) {
        bf16x8 a = *(const bf16x8*)&xrow[kk*32 + quad*8];
        #pragma unroll
        for (int t = 0; t < 4; ++t) {
            bf16x8 bw = *(bf16x8*)&WT[(t*16 + l15) * 264 + kk*32 + quad*8];
            acc[t] = __builtin_amdgcn_mfma_f32_16x16x32_bf16(a, bw, acc[t], 0,0,0);
        }
    }
    #pragma unroll
    for (int t = 0; t < 4; ++t) {
        int j = c0 + t*16 + l15;
        float bias = bp[j];
        #pragma unroll
        for (int r = 0; r < 4; ++r) {
            int row = r0 + wid*16 + quad*4 + r;
            out[(size_t)row * C_ + j] = acc[t][r] + bias;
        }
    }
}

extern "C" void kernel_launch(void* const* d_in, const int* in_sizes, int n_in,
                              void* d_out, int out_size, void* d_ws, size_t ws_size,
                              hipStream_t stream)
{
    const float* x  = (const float*)d_in[0];
    const float* Wq = (const float*)d_in[1];
    const float* Wp = (const float*)d_in[2];
    const float* bp = (const float*)d_in[3];
    float* out  = (float*)d_out;
    float* wout = out + (size_t)B_ * N_ * C_;   // weights output after x_out

    char* ws = (char*)d_ws;
    short* qbf  = (short*)ws;                                   // 4 MB
    short* kbf  = qbf  + (size_t)B_*H_*N_*DH_;                  // 4 MB
    short* vtbf = kbf  + (size_t)B_*H_*N_*DH_;                  // 4 MB
    float* zrecip = (float*)(vtbf + (size_t)B_*H_*N_*DH_);      // 256 KB
    short* xc   = (short*)(zrecip + (size_t)B_*H_*N_);          // 4 MB

    k_qkv <<<dim3(6, 128),  256, 0, stream>>>(x, Wq, qbf, kbf, vtbf);
    k_zsum<<<dim3(32, 32),  256, 0, stream>>>(qbf, kbf, zrecip);
    k_attn<<<dim3(32, 32),  256, 0, stream>>>(qbf, kbf, vtbf, zrecip, wout, xc);
    k_proj<<<dim3(4, 128),  256, 0, stream>>>(xc, Wp, bp, out);
}

// Round 3
// 686.421 us; speedup vs baseline: 1.0665x; 1.0665x over previous
//
#include <hip/hip_runtime.h>
#include <hip/hip_bf16.h>

#define B_ 4
#define N_ 2048
#define C_ 256
#define H_ 8
#define DH_ 32
#define SCALE_ 0.17677669529663687f

typedef __attribute__((ext_vector_type(8))) short bf16x8;
typedef __attribute__((ext_vector_type(4))) float f32x4;

__device__ __forceinline__ short f2bf(float f) {
    union { float f; unsigned u; } v; v.f = f;
    unsigned r = v.u + 0x7fffu + ((v.u >> 16) & 1u);
    return (short)(r >> 16);
}
__device__ __forceinline__ float bf2f(short s) {
    union { unsigned u; float f; } v; v.u = ((unsigned)(unsigned short)s) << 16;
    return v.f;
}
// pack 8 fp32 -> bf16x8 via v_cvt_pk_bf16_f32 (RNE, matches f2bf)
__device__ __forceinline__ bf16x8 cvt_pk8(f32x4 a, f32x4 b) {
    union { unsigned u[4]; bf16x8 v; } r;
    asm("v_cvt_pk_bf16_f32 %0, %1, %2" : "=v"(r.u[0]) : "v"(a[0]), "v"(a[1]));
    asm("v_cvt_pk_bf16_f32 %0, %1, %2" : "=v"(r.u[1]) : "v"(a[2]), "v"(a[3]));
    asm("v_cvt_pk_bf16_f32 %0, %1, %2" : "=v"(r.u[2]) : "v"(b[0]), "v"(b[1]));
    asm("v_cvt_pk_bf16_f32 %0, %1, %2" : "=v"(r.u[3]) : "v"(b[2]), "v"(b[3]));
    return r.v;
}

// ---------------- K1: QKV projection (hi/lo split bf16 MFMA) ----------------
// x[8192,256] @ W_qkv[256,768] -> q(scaled),k bf16 [bh][n][32], v transposed [bh][32][n]
// W-transpose LDS staging is XOR-swizzled on the wrow 8-block (bits 3-4) keyed by
// (col>>4)&3 == seg&3: breaks the 16-way same-bank conflict of the scattered
// ds_write_b16 transpose down to ~4-way, while fragment reads stay contiguous
// (read block index quad ^ (t&3), data order within block preserved).
__global__ __launch_bounds__(256) void k_qkv(
    const float* __restrict__ x, const float* __restrict__ Wq,
    short* __restrict__ qbf, short* __restrict__ kbf, short* __restrict__ vtbf)
{
    __shared__ __align__(16) short XSh[64*40], XSl[64*40];   // 64 rows x 32, stride 40 (80B)
    __shared__ __align__(16) short WTh[128*40], WTl[128*40]; // 128 cols x 32k, transposed+swizzled
    const int tid = threadIdx.x;
    const int wid = tid >> 6, lane = tid & 63;
    const int l15 = lane & 15, quad = lane >> 4;
    const int r0 = blockIdx.y * 64;
    const int c0 = blockIdx.x * 128;

    f32x4 acc[8];
    #pragma unroll
    for (int t = 0; t < 8; ++t) acc[t] = (f32x4){0.f,0.f,0.f,0.f};

    for (int kk = 0; kk < 8; ++kk) {
        const int k0 = kk * 32;
        { // stage X tile 64x32 fp32 -> hi/lo bf16
            int row = tid >> 2, cg = tid & 3;
            const float* xp = &x[(size_t)(r0 + row) * C_ + k0 + cg * 8];
            float4 a = *(const float4*)xp;
            float4 b = *(const float4*)(xp + 4);
            float vals[8] = {a.x,a.y,a.z,a.w,b.x,b.y,b.z,b.w};
            short hi[8], lo[8];
            #pragma unroll
            for (int i = 0; i < 8; ++i) {
                hi[i] = f2bf(vals[i]);
                lo[i] = f2bf(vals[i] - bf2f(hi[i]));
            }
            *(bf16x8*)&XSh[row*40 + cg*8] = *(bf16x8*)hi;
            *(bf16x8*)&XSl[row*40 + cg*8] = *(bf16x8*)lo;
        }
        { // stage W tile 32x128 transposed, swizzled
            int wrow = tid >> 3, seg = tid & 7;
            const int swz = (seg & 3) << 3;          // == ((col>>4)&3)<<3 for all cols below
            const int wsw = wrow ^ swz;
            const float* wp = &Wq[(size_t)(k0 + wrow) * (3*C_) + c0 + seg*16];
            #pragma unroll
            for (int q4 = 0; q4 < 4; ++q4) {
                float4 wv = *(const float4*)(wp + q4*4);
                float wa[4] = {wv.x, wv.y, wv.z, wv.w};
                #pragma unroll
                for (int i = 0; i < 4; ++i) {
                    int col = seg*16 + q4*4 + i;
                    short hb = f2bf(wa[i]);
                    WTh[col*40 + wsw] = hb;
                    WTl[col*40 + wsw] = f2bf(wa[i] - bf2f(hb));
                }
            }
        }
        __syncthreads();
        bf16x8 ah = *(bf16x8*)&XSh[(wid*16 + l15)*40 + quad*8];
        bf16x8 al = *(bf16x8*)&XSl[(wid*16 + l15)*40 + quad*8];
        #pragma unroll
        for (int t = 0; t < 8; ++t) {
            const int rb = (quad*8) ^ ((t & 3) << 3);   // de-swizzled k-block
            bf16x8 bh = *(bf16x8*)&WTh[(t*16 + l15)*40 + rb];
            bf16x8 bl = *(bf16x8*)&WTl[(t*16 + l15)*40 + rb];
            acc[t] = __builtin_amdgcn_mfma_f32_16x16x32_bf16(ah, bh, acc[t], 0,0,0);
            acc[t] = __builtin_amdgcn_mfma_f32_16x16x32_bf16(ah, bl, acc[t], 0,0,0);
            acc[t] = __builtin_amdgcn_mfma_f32_16x16x32_bf16(al, bh, acc[t], 0,0,0);
        }
        __syncthreads();
    }
    // scatter store: col j -> (which, h, d)
    #pragma unroll
    for (int t = 0; t < 8; ++t) {
        int j = c0 + t*16 + l15;
        int which = j >> 8, h = (j >> 5) & 7, d = j & 31;
        #pragma unroll
        for (int r = 0; r < 4; ++r) {
            int tok = r0 + wid*16 + quad*4 + r;
            int b = tok >> 11, n = tok & (N_-1);
            float val = acc[t][r];
            int bh = b * H_ + h;
            if (which == 0)      qbf[((size_t)bh * N_ + n) * DH_ + d] = f2bf(val * SCALE_);
            else if (which == 1) kbf[((size_t)bh * N_ + n) * DH_ + d] = f2bf(val);
            else                 vtbf[((size_t)bh * DH_ + d) * N_ + n] = f2bf(val);
        }
    }
}

// ---------------- K2: fused attention: in-register Z phase, then P/PV/local ----------------
__global__ __launch_bounds__(256) void k_attn(
    const short* __restrict__ qbf, const short* __restrict__ kbf,
    const short* __restrict__ vtbf,
    float* __restrict__ wout, short* __restrict__ xc)
{
    // per-wave fp32 normalized P tile [16 rows][32 cols], row stride 36 floats (144B):
    //  - writes (row=quad*4+r, col=l15 / 16+l15): banks (16(q&1)+4r+l15)%32 -> exactly 2-way = free
    //  - reads  (row=l15, cols=quad*8..+7) as 2x ds_read_b128, 16B-aligned
    __shared__ __align__(16) float pt[4][16*36];
    const int tid = threadIdx.x;
    const int wid = tid >> 6, lane = tid & 63;
    const int l15 = lane & 15, quad = lane >> 4;
    const int bh = blockIdx.y;
    const int b = bh >> 3, h = bh & 7;
    const int q0 = blockIdx.x * 64 + wid * 16;
    const int w = q0 >> 4;            // local window index (16 rows == 1 window)
    const int mtd = w >> 1, hl = w & 1;

    bf16x8 aq = *(const bf16x8*)&qbf[((size_t)bh * N_ + q0 + l15) * DH_ + quad * 8];

    const short* kbase = &kbf[(size_t)bh * N_ * DH_];
    const short* vbase = &vtbf[(size_t)bh * DH_ * N_];
    float* wbase = &wout[((size_t)bh * N_ + q0) * N_];

    // ---- phase 0: softmax denominators in registers (replaces k_zsum kernel) ----
    float zs[4] = {0.f, 0.f, 0.f, 0.f};
    for (int mt = 0; mt < N_/32; ++mt) {
        const int m0 = mt * 32;
        bf16x8 bk0 = *(const bf16x8*)&kbase[(size_t)(m0 + l15) * DH_ + quad * 8];
        bf16x8 bk1 = *(const bf16x8*)&kbase[(size_t)(m0 + 16 + l15) * DH_ + quad * 8];
        f32x4 S0 = __builtin_amdgcn_mfma_f32_16x16x32_bf16(aq, bk0, (f32x4){0,0,0,0}, 0,0,0);
        f32x4 S1 = __builtin_amdgcn_mfma_f32_16x16x32_bf16(aq, bk1, (f32x4){0,0,0,0}, 0,0,0);
        #pragma unroll
        for (int r = 0; r < 4; ++r) { zs[r] += __expf(S0[r]); zs[r] += __expf(S1[r]); }
    }
    float zr[4];
    #pragma unroll
    for (int r = 0; r < 4; ++r) {
        for (int off = 1; off < 16; off <<= 1)
            zs[r] += __shfl_xor(zs[r], off, 64);   // reduce across l15 within quad group
        zr[r] = 1.0f / zs[r];
    }

    // ---- main loop ----
    f32x4 O0 = {0,0,0,0}, O1 = {0,0,0,0};
    float pl[4] = {0.f,0.f,0.f,0.f};
    float* myp = pt[wid];
    float*       wr0  = &myp[(quad*4)*36 + l15];     // + r*36 (+16 for upper 16 cols)
    const float* rd   = &myp[l15*36 + quad*8];       // row l15, 8 floats at col quad*8

    for (int mt = 0; mt < N_/32; ++mt) {
        const int m0 = mt * 32;
        bf16x8 bk0 = *(const bf16x8*)&kbase[(size_t)(m0 + l15) * DH_ + quad * 8];
        bf16x8 bk1 = *(const bf16x8*)&kbase[(size_t)(m0 + 16 + l15) * DH_ + quad * 8];
        f32x4 S0 = __builtin_amdgcn_mfma_f32_16x16x32_bf16(aq, bk0, (f32x4){0,0,0,0}, 0,0,0);
        f32x4 S1 = __builtin_amdgcn_mfma_f32_16x16x32_bf16(aq, bk1, (f32x4){0,0,0,0}, 0,0,0);
        float p0[4], p1[4];
        #pragma unroll
        for (int r = 0; r < 4; ++r) { p0[r] = __expf(S0[r]); p1[r] = __expf(S1[r]); }
        if (mt == mtd) {
            #pragma unroll
            for (int r = 0; r < 4; ++r) pl[r] = hl ? p1[r] : p0[r];
        }
        // register-sourced coalesced wout stores (full 64B segments per instr) + fp32 LDS tile
        #pragma unroll
        for (int r = 0; r < 4; ++r) {
            float wp0 = p0[r] * zr[r];
            float wp1 = p1[r] * zr[r];
            float* wrow = wbase + (size_t)(quad*4 + r) * N_ + m0;
            wrow[l15]      = wp0;
            wrow[16 + l15] = wp1;
            wr0[r*36]      = wp0;
            wr0[r*36 + 16] = wp1;
        }
        // LDS transpose readback feeds the PV A-fragment via packed cvt
        f32x4 pa0 = *(const f32x4*)rd;
        f32x4 pa1 = *(const f32x4*)(rd + 4);
        bf16x8 ap = cvt_pk8(pa0, pa1);
        bf16x8 bv0 = *(const bf16x8*)&vbase[(size_t)l15 * N_ + m0 + quad*8];
        bf16x8 bv1 = *(const bf16x8*)&vbase[(size_t)(16 + l15) * N_ + m0 + quad*8];
        O0 = __builtin_amdgcn_mfma_f32_16x16x32_bf16(ap, bv0, O0, 0,0,0);
        O1 = __builtin_amdgcn_mfma_f32_16x16x32_bf16(ap, bv1, O1, 0,0,0);
    }

    // local window attention (reuses stashed diagonal exp tile, unnormalized)
    float zl[4];
    #pragma unroll
    for (int r = 0; r < 4; ++r) {
        zl[r] = pl[r];
        for (int off = 1; off < 16; off <<= 1)
            zl[r] += __shfl_xor(zl[r], off, 64);
    }
    #pragma unroll
    for (int r = 0; r < 4; ++r) {
        float pn = pl[r] / zl[r];
        wr0[r*36]      = hl ? 0.f : pn;
        wr0[r*36 + 16] = hl ? pn : 0.f;
    }
    {
        const int m0 = mtd * 32;
        f32x4 pa0 = *(const f32x4*)rd;
        f32x4 pa1 = *(const f32x4*)(rd + 4);
        bf16x8 ap = cvt_pk8(pa0, pa1);
        bf16x8 bv0 = *(const bf16x8*)&vbase[(size_t)l15 * N_ + m0 + quad*8];
        bf16x8 bv1 = *(const bf16x8*)&vbase[(size_t)(16 + l15) * N_ + m0 + quad*8];
        O0 = __builtin_amdgcn_mfma_f32_16x16x32_bf16(ap, bv0, O0, 0,0,0);
        O1 = __builtin_amdgcn_mfma_f32_16x16x32_bf16(ap, bv1, O1, 0,0,0);
    }
    // store x_comb (bf16) in [B,N,C] head-merged layout
    #pragma unroll
    for (int r = 0; r < 4; ++r) {
        int n = q0 + quad*4 + r;
        short* xrow = &xc[((size_t)(b * N_ + n)) * C_ + h * DH_];
        xrow[l15]      = f2bf(O0[r]);
        xrow[16 + l15] = f2bf(O1[r]);
    }
}

// ---------------- K3: output projection + bias ----------------
__global__ __launch_bounds__(256) void k_proj(
    const short* __restrict__ xc, const float* __restrict__ Wp,
    const float* __restrict__ bp, float* __restrict__ out)
{
    __shared__ __align__(16) short WT[64 * 264];  // 64 cols x 256 k, stride 528B
    const int tid = threadIdx.x;
    const int wid = tid >> 6, lane = tid & 63;
    const int l15 = lane & 15, quad = lane >> 4;
    const int c0 = blockIdx.x * 64;
    const int r0 = blockIdx.y * 64;

    { // stage W_proj[:, c0:c0+64] transposed (bank-free: 2 lanes/bank on writes)
        int k = tid;
        const float* wp = &Wp[(size_t)k * C_ + c0];
        #pragma unroll
        for (int s = 0; s < 16; ++s) {
            float4 wv = *(const float4*)(wp + s*4);
            float wa[4] = {wv.x, wv.y, wv.z, wv.w};
            #pragma unroll
            for (int i = 0; i < 4; ++i)
                WT[(s*4 + i) * 264 + k] = f2bf(wa[i]);
        }
    }
    __syncthreads();

    f32x4 acc[4];
    #pragma unroll
    for (int t = 0; t < 4; ++t) acc[t] = (f32x4){0,0,0,0};
    const short* xrow = &xc[(size_t)(r0 + wid*16 + l15) * C_];
    #pragma unroll
    for (int kk = 0; kk < 8; ++kk) {
        bf16x8 a = *(const bf16x8*)&xrow[kk*32 + quad*8];
        #pragma unroll
        for (int t = 0; t < 4; ++t) {
            bf16x8 bw = *(bf16x8*)&WT[(t*16 + l15) * 264 + kk*32 + quad*8];
            acc[t] = __builtin_amdgcn_mfma_f32_16x16x32_bf16(a, bw, acc[t], 0,0,0);
        }
    }
    #pragma unroll
    for (int t = 0; t < 4; ++t) {
        int j = c0 + t*16 + l15;
        float bias = bp[j];
        #pragma unroll
        for (int r = 0; r < 4; ++r) {
            int row = r0 + wid*16 + quad*4 + r;
            out[(size_t)row * C_ + j] = acc[t][r] + bias;
        }
    }
}

extern "C" void kernel_launch(void* const* d_in, const int* in_sizes, int n_in,
                              void* d_out, int out_size, void* d_ws, size_t ws_size,
                              hipStream_t stream)
{
    const float* x  = (const float*)d_in[0];
    const float* Wq = (const float*)d_in[1];
    const float* Wp = (const float*)d_in[2];
    const float* bp = (const float*)d_in[3];
    float* out  = (float*)d_out;
    float* wout = out + (size_t)B_ * N_ * C_;   // weights output after x_out

    char* ws = (char*)d_ws;
    short* qbf  = (short*)ws;                                   // 4 MB
    short* kbf  = qbf  + (size_t)B_*H_*N_*DH_;                  // 4 MB
    short* vtbf = kbf  + (size_t)B_*H_*N_*DH_;                  // 4 MB
    short* xc   = vtbf + (size_t)B_*H_*N_*DH_;                  // 4 MB

    k_qkv <<<dim3(6, 128),  256, 0, stream>>>(x, Wq, qbf, kbf, vtbf);
    k_attn<<<dim3(32, 32),  256, 0, stream>>>(qbf, kbf, vtbf, wout, xc);
    k_proj<<<dim3(4, 128),  256, 0, stream>>>(xc, Wp, bp, out);
}